// Round 12
// baseline (438.780 us; speedup 1.0000x reference)
//
#include <hip/hip_runtime.h>

#define NN 50000
#define EE 800000
#define DD 128
#define RR 8
#define CELLS (NN * RR)            // 400000 (dst, rel) cells, key = dst*8 + rel
#define TILE_N 64
#define NBLK ((NN + TILE_N - 1) / TILE_N)          // 782
#define SCAN_CHUNK 1024
#define SCAN_BLOCKS ((CELLS + SCAN_CHUNK - 1) / SCAN_CHUNK)   // 391

typedef __attribute__((ext_vector_type(4))) float f32x4;
typedef __attribute__((ext_vector_type(8))) short s16x8;
union ABu { uint4 q; s16x8 v; };

// ---------------- bf16 helpers ----------------

__device__ __forceinline__ unsigned int packbf2(float a, float b) {
    unsigned int ua = __float_as_uint(a);
    unsigned int ub = __float_as_uint(b);
    ua = (ua + 0x7fffu + ((ua >> 16) & 1u)) >> 16;           // RNE, low half
    ub = (ub + 0x7fffu + ((ub >> 16) & 1u)) & 0xffff0000u;   // RNE, high half
    return ua | ub;
}

// unpack 4 uint4 (32 bf16), weighted-add into sA[0..31] (w is 0 or 1)
__device__ __forceinline__ void upaddw(float* sA, const uint4* U, float w) {
#pragma unroll
    for (int i = 0; i < 4; ++i) {
        unsigned int uu[4] = {U[i].x, U[i].y, U[i].z, U[i].w};
#pragma unroll
        for (int j2 = 0; j2 < 4; ++j2) {
            int idx = i * 8 + j2 * 2;
            sA[idx]     = fmaf(__uint_as_float(uu[j2] << 16),         w, sA[idx]);
            sA[idx + 1] = fmaf(__uint_as_float(uu[j2] & 0xffff0000u), w, sA[idx + 1]);
        }
    }
}

__global__ void to_bf16(const float* __restrict__ in, unsigned int* __restrict__ ob,
                        int npair) {
    int i = blockIdx.x * blockDim.x + threadIdx.x;
    if (i < npair) {
        float2 v = ((const float2*)in)[i];
        ob[i] = packbf2(v.x, v.y);
    }
}

// pack W [16 blocks of 64x64, row-major (k, n)] -> Wb [block][n][kp] bf16 pairs
__global__ void wpack(const float* __restrict__ W1, const float* __restrict__ W2,
                      unsigned int* __restrict__ Wb1, unsigned int* __restrict__ Wb2) {
    int i = blockIdx.x * blockDim.x + threadIdx.x;     // 32768
    int kp = i & 31, n = (i >> 5) & 63, rb = i >> 11;
    int s0 = (rb * 64 + 2 * kp) * 64 + n;
    int s1 = (rb * 64 + 2 * kp + 1) * 64 + n;
    Wb1[((rb * 64 + n) * 32) + kp] = packbf2(W1[s0], W1[s1]);
    Wb2[((rb * 64 + n) * 32) + kp] = packbf2(W2[s0], W2[s1]);
}

// pack root [128k x 128n] -> rb [n][kp]
__global__ void rpack(const float* __restrict__ r1, const float* __restrict__ r2,
                      unsigned int* __restrict__ rb1, unsigned int* __restrict__ rb2) {
    int i = blockIdx.x * blockDim.x + threadIdx.x;     // 8192
    int kp = i & 63, n = i >> 6;
    int s0 = (2 * kp) * 128 + n, s1 = (2 * kp + 1) * 128 + n;
    rb1[n * 64 + kp] = packbf2(r1[s0], r1[s1]);
    rb2[n * 64 + kp] = packbf2(r2[s0], r2[s1]);
}

// ---------------- prep: counting sort into CSR by cell = dst*8 + rel ----------------

__global__ void count_cells(const int* __restrict__ dst, const int* __restrict__ et,
                            int* __restrict__ cnt) {
    int e = blockIdx.x * blockDim.x + threadIdx.x;
    if (e < EE) atomicAdd(&cnt[dst[e] * RR + et[e]], 1);
}

__global__ __launch_bounds__(256) void scan1(const int* __restrict__ cnt,
                                             int* __restrict__ off, int* __restrict__ bsum) {
    __shared__ int s[256];
    int tid = threadIdx.x;
    int base = blockIdx.x * SCAN_CHUNK + tid * 4;
    int v[4];
#pragma unroll
    for (int i = 0; i < 4; ++i) v[i] = (base + i < CELLS) ? cnt[base + i] : 0;
    int tot = v[0] + v[1] + v[2] + v[3];
    s[tid] = tot;
    __syncthreads();
    for (int d = 1; d < 256; d <<= 1) {
        int t = (tid >= d) ? s[tid - d] : 0;
        __syncthreads();
        s[tid] += t;
        __syncthreads();
    }
    int excl = s[tid] - tot;
    if (tid == 255) bsum[blockIdx.x] = s[255];
    int run = excl;
#pragma unroll
    for (int i = 0; i < 4; ++i) {
        if (base + i < CELLS) off[base + i] = run;
        run += v[i];
    }
}

__global__ __launch_bounds__(512) void scan2(int* __restrict__ bsum) {
    __shared__ int s[512];
    int tid = threadIdx.x;
    int v = (tid < SCAN_BLOCKS) ? bsum[tid] : 0;
    s[tid] = v;
    __syncthreads();
    for (int d = 1; d < 512; d <<= 1) {
        int t = (tid >= d) ? s[tid - d] : 0;
        __syncthreads();
        s[tid] += t;
        __syncthreads();
    }
    if (tid < SCAN_BLOCKS) bsum[tid] = s[tid] - v;
}

__global__ __launch_bounds__(256) void scan3(int* __restrict__ off, const int* __restrict__ bsum,
                                             int* __restrict__ cur) {
    int base = blockIdx.x * SCAN_CHUNK + threadIdx.x * 4;
    int add = bsum[blockIdx.x];
#pragma unroll
    for (int i = 0; i < 4; ++i) {
        int c = base + i;
        if (c < CELLS) {
            int o = off[c] + add;
            off[c] = o;
            cur[c] = o;
        }
    }
    if (blockIdx.x == 0 && threadIdx.x == 0) off[CELLS] = EE;   // sentinel
}

__global__ void cell_scatter(const int* __restrict__ src, const int* __restrict__ dst,
                             const int* __restrict__ et, int* __restrict__ cur,
                             int* __restrict__ esrc) {
    int e = blockIdx.x * blockDim.x + threadIdx.x;
    if (e < EE) {
        int cell = dst[e] * RR + et[e];
        int pos = atomicAdd(&cur[cell], 1);
        esrc[pos] = src[e];
    }
}

// ---------------- fused layer, MFMA GEMM ----------------
// Gather -> packed bf16 MTb[kp][66] in LDS -> mfma_f32_16x16x32_bf16 with B-frags
// loaded straight from pre-packed global Wb/rootb (L1-hot). Gather uses predicated
// unroll-2 with NEXT-pair index prefetch (index load off the dependent chain).
// LDS: SH 40KB union {MTb 64x66 uint (17KB), OUT 64x130 float (33KB)} -> 4 blk/CU.
template <int RELU, int WRITEF, int WRITEB>
__global__ __launch_bounds__(256, 4) void layer_fused(
    const unsigned int* __restrict__ xgb, const int* __restrict__ esrc,
    const int* __restrict__ off,
    const unsigned int* __restrict__ Wb, const unsigned int* __restrict__ rootb,
    const float* __restrict__ bias, float* __restrict__ outf,
    unsigned int* __restrict__ outb) {

    __shared__ unsigned int SH[10240];      // 40960 B

    int tid = threadIdx.x;
    int n0 = blockIdx.x * TILE_N;
    int e = tid & 63, q = tid >> 6;         // gather: lane-node, wave k-quarter
    int w = tid >> 6, l = tid & 63;         // gemm: wave, lane
    int quad = l >> 4, li = l & 15;
    int b = w >> 1;                          // out-half this wave serves

    f32x4 acc[4][2];
#pragma unroll
    for (int s = 0; s < 2; ++s) {
        float bv = bias[32 * w + 16 * s + li];
#pragma unroll
        for (int mt = 0; mt < 4; ++mt) {
            acc[mt][s][0] = bv; acc[mt][s][1] = bv; acc[mt][s][2] = bv; acc[mt][s][3] = bv;
        }
    }

    int node = n0 + e;

    for (int r = 0; r < RR; ++r) {
        // ---- gather mean (bf16 payload, fp32 accum), wave q owns k in [32q,32q+32) ----
        float sA[32];
#pragma unroll
        for (int i = 0; i < 32; ++i) sA[i] = 0.f;
        int ne = 0;
        if (node < NN) {
            int cell = node * RR + r;
            int o = off[cell];
            ne = off[cell + 1] - o;
            if (ne > 0) {
                int last = o + ne - 1;
                int s0 = esrc[o];
                int s1 = esrc[min(o + 1, last)];
                for (int t2 = 0; t2 < ne; t2 += 2) {
                    const uint4* p0 = (const uint4*)(xgb + (size_t)s0 * 64 + q * 16);
                    const uint4* p1 = (const uint4*)(xgb + (size_t)s1 * 64 + q * 16);
                    uint4 U0[4] = {p0[0], p0[1], p0[2], p0[3]};
                    uint4 U1[4] = {p1[0], p1[1], p1[2], p1[3]};
                    float w1 = (t2 + 1 < ne) ? 1.f : 0.f;
                    if (t2 + 2 < ne) {               // prefetch next pair's indices
                        s0 = esrc[o + t2 + 2];
                        s1 = esrc[min(o + t2 + 3, last)];
                    }
                    upaddw(sA, U0, 1.f);
                    upaddw(sA, U1, w1);
                }
            }
        }
        float sc = 1.0f / (float)max(ne, 1);
#pragma unroll
        for (int i = 0; i < 16; ++i)
            SH[(16 * q + i) * 66 + e] = packbf2(sA[2 * i] * sc, sA[2 * i + 1] * sc);
        __syncthreads();

        // ---- block-diag GEMM: 16 mfma/wave; A from MTb, B from global Wb (L1-hot) ----
        const uint4* WbB = (const uint4*)(Wb + (((size_t)r * 2 + b) * 64) * 32);
        int nl0 = (w & 1) * 32 + li;         // nloc for s=0
#pragma unroll
        for (int kc = 0; kc < 2; ++kc) {
            ABu bf0, bf1;
            bf0.q = WbB[nl0 * 8 + 4 * kc + quad];
            bf1.q = WbB[(nl0 + 16) * 8 + 4 * kc + quad];
#pragma unroll
            for (int mt = 0; mt < 4; ++mt) {
                ABu af;
                int base = (32 * b + 16 * kc + 4 * quad) * 66 + 16 * mt + li;
                af.q.x = SH[base]; af.q.y = SH[base + 66];
                af.q.z = SH[base + 132]; af.q.w = SH[base + 198];
                acc[mt][0] = __builtin_amdgcn_mfma_f32_16x16x32_bf16(af.v, bf0.v, acc[mt][0], 0, 0, 0);
                acc[mt][1] = __builtin_amdgcn_mfma_f32_16x16x32_bf16(af.v, bf1.v, acc[mt][1], 0, 0, 0);
            }
        }
        __syncthreads();
    }

    // ---- root term: MTb <- own row (already packed bf16: direct copy) ----
    if (node < NN) {
        const uint4* xr = (const uint4*)(xgb + (size_t)node * 64 + q * 16);
        uint4 X[4] = {xr[0], xr[1], xr[2], xr[3]};
#pragma unroll
        for (int i = 0; i < 4; ++i) {
            SH[(16 * q + 4 * i + 0) * 66 + e] = X[i].x;
            SH[(16 * q + 4 * i + 1) * 66 + e] = X[i].y;
            SH[(16 * q + 4 * i + 2) * 66 + e] = X[i].z;
            SH[(16 * q + 4 * i + 3) * 66 + e] = X[i].w;
        }
    } else {
#pragma unroll
        for (int i = 0; i < 16; ++i) SH[(16 * q + i) * 66 + e] = 0u;
    }
    __syncthreads();

    // root GEMM: K=128 -> 4 k-chunks, 32 mfma/wave
    const uint4* RbB = (const uint4*)rootb;
#pragma unroll
    for (int kc = 0; kc < 4; ++kc) {
        ABu bf0, bf1;
        bf0.q = RbB[(32 * w + li) * 16 + 4 * kc + quad];
        bf1.q = RbB[(32 * w + 16 + li) * 16 + 4 * kc + quad];
#pragma unroll
        for (int mt = 0; mt < 4; ++mt) {
            ABu af;
            int base = (16 * kc + 4 * quad) * 66 + 16 * mt + li;
            af.q.x = SH[base]; af.q.y = SH[base + 66];
            af.q.z = SH[base + 132]; af.q.w = SH[base + 198];
            acc[mt][0] = __builtin_amdgcn_mfma_f32_16x16x32_bf16(af.v, bf0.v, acc[mt][0], 0, 0, 0);
            acc[mt][1] = __builtin_amdgcn_mfma_f32_16x16x32_bf16(af.v, bf1.v, acc[mt][1], 0, 0, 0);
        }
    }
    __syncthreads();

    // ---- epilogue: stage D to LDS (fp32, stride 130), then coalesced stores ----
    float* OF = (float*)SH;
#pragma unroll
    for (int mt = 0; mt < 4; ++mt)
#pragma unroll
        for (int s = 0; s < 2; ++s)
#pragma unroll
            for (int reg = 0; reg < 4; ++reg)
                OF[(16 * mt + 4 * quad + reg) * 130 + 32 * w + 16 * s + li] = acc[mt][s][reg];
    __syncthreads();

    if (WRITEB) {
        int p = tid & 63, rg = tid >> 6;     // pair-col, row-group (4 rows/pass)
#pragma unroll 4
        for (int it = 0; it < 16; ++it) {
            int ee = it * 4 + rg, row = n0 + ee;
            if (row < NN) {
                float v0 = OF[ee * 130 + 2 * p], v1 = OF[ee * 130 + 2 * p + 1];
                if (RELU) { v0 = fmaxf(v0, 0.f); v1 = fmaxf(v1, 0.f); }
                outb[(size_t)row * 64 + p] = packbf2(v0, v1);
            }
        }
    }
    if (WRITEF) {
        int d4 = (tid & 31) * 4, rg = tid >> 5;   // 8 rows/pass
#pragma unroll 4
        for (int it = 0; it < 8; ++it) {
            int ee = it * 8 + rg, row = n0 + ee;
            if (row < NN) {
                float4 v = make_float4(OF[ee * 130 + d4], OF[ee * 130 + d4 + 1],
                                       OF[ee * 130 + d4 + 2], OF[ee * 130 + d4 + 3]);
                if (RELU) {
                    v.x = fmaxf(v.x, 0.f); v.y = fmaxf(v.y, 0.f);
                    v.z = fmaxf(v.z, 0.f); v.w = fmaxf(v.w, 0.f);
                }
                *(float4*)(outf + (size_t)row * DD + d4) = v;
            }
        }
    }
}

// ---------------- driver ----------------

extern "C" void kernel_launch(void* const* d_in, const int* in_sizes, int n_in,
                              void* d_out, int out_size, void* d_ws, size_t ws_size,
                              hipStream_t stream) {
    const float* x     = (const float*)d_in[0];
    const int*   ei    = (const int*)d_in[1];
    const int*   src   = ei;
    const int*   dstp  = ei + EE;
    const int*   et    = (const int*)d_in[2];
    const float* W1    = (const float*)d_in[3];
    const float* root1 = (const float*)d_in[4];
    const float* b1    = (const float*)d_in[5];
    const float* W2    = (const float*)d_in[6];
    const float* root2 = (const float*)d_in[7];
    const float* b2    = (const float*)d_in[8];
    float* out = (float*)d_out;

    // ws layout (4 B elements)
    unsigned int* xb  = (unsigned int*)d_ws;         // NN*64 packed bf16 pairs
    unsigned int* hb  = xb + (size_t)NN * 64;        // NN*64
    int* cnt  = (int*)(hb + (size_t)NN * 64);        // CELLS
    int* off  = cnt + CELLS;                         // CELLS + 1
    int* cur  = off + CELLS + 1;                     // CELLS
    int* bsum = cur + CELLS;                         // 512
    int* esrc = bsum + 512;                          // EE
    unsigned int* Wb1 = (unsigned int*)(esrc + EE);  // 32768
    unsigned int* Wb2 = Wb1 + 32768;                 // 32768
    unsigned int* rb1 = Wb2 + 32768;                 // 8192
    unsigned int* rb2 = rb1 + 8192;                  // 8192

    hipMemsetAsync(cnt, 0, CELLS * sizeof(int), stream);
    to_bf16<<<(NN * 64 + 255) / 256, 256, 0, stream>>>(x, xb, NN * 64);
    wpack<<<128, 256, 0, stream>>>(W1, W2, Wb1, Wb2);
    rpack<<<32, 256, 0, stream>>>(root1, root2, rb1, rb2);
    count_cells<<<(EE + 255) / 256, 256, 0, stream>>>(dstp, et, cnt);
    scan1<<<SCAN_BLOCKS, 256, 0, stream>>>(cnt, off, bsum);
    scan2<<<1, 512, 0, stream>>>(bsum);
    scan3<<<SCAN_BLOCKS, 256, 0, stream>>>(off, bsum, cur);
    cell_scatter<<<(EE + 255) / 256, 256, 0, stream>>>(src, dstp, et, cur, esrc);

    // layer 1: bf16 h out;  layer 2: fp32 out
    layer_fused<1, 0, 1><<<NBLK, 256, 0, stream>>>(xb, esrc, off, Wb1, rb1, b1,
                                                   nullptr, hb);
    layer_fused<0, 1, 0><<<NBLK, 256, 0, stream>>>(hb, esrc, off, Wb2, rb2, b2,
                                                   out, nullptr);
}

// Round 13
// 388.652 us; speedup vs baseline: 1.1290x; 1.1290x over previous
//
#include <hip/hip_runtime.h>

#define NN 50000
#define EE 800000
#define DD 128
#define RR 8
#define CELLS (NN * RR)            // 400000 (dst, rel) cells, key = dst*8 + rel
#define TILE_N 64
#define NBLK ((NN + TILE_N - 1) / TILE_N)          // 782
#define SCAN_CHUNK 1024
#define SCAN_BLOCKS ((CELLS + SCAN_CHUNK - 1) / SCAN_CHUNK)   // 391

typedef __attribute__((ext_vector_type(4))) float f32x4;
typedef __attribute__((ext_vector_type(8))) short s16x8;
union ABu { uint4 q; s16x8 v; };

// ---------------- bf16 helpers ----------------

__device__ __forceinline__ unsigned int packbf2(float a, float b) {
    unsigned int ua = __float_as_uint(a);
    unsigned int ub = __float_as_uint(b);
    ua = (ua + 0x7fffu + ((ua >> 16) & 1u)) >> 16;           // RNE, low half
    ub = (ub + 0x7fffu + ((ub >> 16) & 1u)) & 0xffff0000u;   // RNE, high half
    return ua | ub;
}

// unpack 4 uint4 (32 bf16) and add into sA[0..31]
__device__ __forceinline__ void upadd(float* sA, const uint4* U) {
#pragma unroll
    for (int i = 0; i < 4; ++i) {
        unsigned int uu[4] = {U[i].x, U[i].y, U[i].z, U[i].w};
#pragma unroll
        for (int j2 = 0; j2 < 4; ++j2) {
            int w = i * 8 + j2 * 2;
            sA[w]     += __uint_as_float(uu[j2] << 16);
            sA[w + 1] += __uint_as_float(uu[j2] & 0xffff0000u);
        }
    }
}

// ---------------- fused prep: to_bf16 + wpack + rpack + count_cells ----------------
// Independent tasks partitioned by block range; one launch instead of four.
#define NB_A ((NN * 64 + 255) / 256)    // 12500: x -> packed bf16
#define NB_B 128                        // wpack: 32768 items
#define NB_C 32                         // rpack: 8192 items
#define NB_D ((EE + 255) / 256)         // 3125: count_cells

__global__ void prep_fused(const float* __restrict__ x, unsigned int* __restrict__ xb,
                           const float* __restrict__ W1, const float* __restrict__ W2,
                           unsigned int* __restrict__ Wb1, unsigned int* __restrict__ Wb2,
                           const float* __restrict__ r1, const float* __restrict__ r2,
                           unsigned int* __restrict__ rb1, unsigned int* __restrict__ rb2,
                           const int* __restrict__ dst, const int* __restrict__ et,
                           int* __restrict__ cnt) {
    int bid = blockIdx.x, tid = threadIdx.x;
    if (bid < NB_A) {
        int i = bid * 256 + tid;
        if (i < NN * 64) {
            float2 v = ((const float2*)x)[i];
            xb[i] = packbf2(v.x, v.y);
        }
    } else if (bid < NB_A + NB_B) {
        // W [16 blocks of 64x64, row-major (k,n)] -> Wb [block][n][kp]
        int i = (bid - NB_A) * 256 + tid;
        int kp = i & 31, n = (i >> 5) & 63, rb = i >> 11;
        int s0 = (rb * 64 + 2 * kp) * 64 + n;
        int s1 = (rb * 64 + 2 * kp + 1) * 64 + n;
        Wb1[((rb * 64 + n) * 32) + kp] = packbf2(W1[s0], W1[s1]);
        Wb2[((rb * 64 + n) * 32) + kp] = packbf2(W2[s0], W2[s1]);
    } else if (bid < NB_A + NB_B + NB_C) {
        // root [128k x 128n] -> rb [n][kp]
        int i = (bid - NB_A - NB_B) * 256 + tid;
        int kp = i & 63, n = i >> 6;
        int s0 = (2 * kp) * 128 + n, s1 = (2 * kp + 1) * 128 + n;
        rb1[n * 64 + kp] = packbf2(r1[s0], r1[s1]);
        rb2[n * 64 + kp] = packbf2(r2[s0], r2[s1]);
    } else {
        int e = (bid - NB_A - NB_B - NB_C) * 256 + tid;
        if (e < EE) atomicAdd(&cnt[dst[e] * RR + et[e]], 1);
    }
}

// ---------------- prep: scans + scatter (CSR by cell = dst*8 + rel) ----------------

__global__ __launch_bounds__(256) void scan1(const int* __restrict__ cnt,
                                             int* __restrict__ off, int* __restrict__ bsum) {
    __shared__ int s[256];
    int tid = threadIdx.x;
    int base = blockIdx.x * SCAN_CHUNK + tid * 4;
    int v[4];
#pragma unroll
    for (int i = 0; i < 4; ++i) v[i] = (base + i < CELLS) ? cnt[base + i] : 0;
    int tot = v[0] + v[1] + v[2] + v[3];
    s[tid] = tot;
    __syncthreads();
    for (int d = 1; d < 256; d <<= 1) {
        int t = (tid >= d) ? s[tid - d] : 0;
        __syncthreads();
        s[tid] += t;
        __syncthreads();
    }
    int excl = s[tid] - tot;
    if (tid == 255) bsum[blockIdx.x] = s[255];
    int run = excl;
#pragma unroll
    for (int i = 0; i < 4; ++i) {
        if (base + i < CELLS) off[base + i] = run;
        run += v[i];
    }
}

__global__ __launch_bounds__(512) void scan2(int* __restrict__ bsum) {
    __shared__ int s[512];
    int tid = threadIdx.x;
    int v = (tid < SCAN_BLOCKS) ? bsum[tid] : 0;
    s[tid] = v;
    __syncthreads();
    for (int d = 1; d < 512; d <<= 1) {
        int t = (tid >= d) ? s[tid - d] : 0;
        __syncthreads();
        s[tid] += t;
        __syncthreads();
    }
    if (tid < SCAN_BLOCKS) bsum[tid] = s[tid] - v;
}

__global__ __launch_bounds__(256) void scan3(int* __restrict__ off, const int* __restrict__ bsum,
                                             int* __restrict__ cur) {
    int base = blockIdx.x * SCAN_CHUNK + threadIdx.x * 4;
    int add = bsum[blockIdx.x];
#pragma unroll
    for (int i = 0; i < 4; ++i) {
        int c = base + i;
        if (c < CELLS) {
            int o = off[c] + add;
            off[c] = o;
            cur[c] = o;
        }
    }
    if (blockIdx.x == 0 && threadIdx.x == 0) off[CELLS] = EE;   // sentinel
}

__global__ void cell_scatter(const int* __restrict__ src, const int* __restrict__ dst,
                             const int* __restrict__ et, int* __restrict__ cur,
                             int* __restrict__ esrc) {
    int e = blockIdx.x * blockDim.x + threadIdx.x;
    if (e < EE) {
        int cell = dst[e] * RR + et[e];
        int pos = atomicAdd(&cur[cell], 1);
        esrc[pos] = src[e];
    }
}

// ---------------- fused layer, MFMA GEMM (round-11 structure) ----------------
// Gather (plain unroll-2) -> packed bf16 MTb[kp][66] in LDS -> mfma_f32_16x16x32_bf16
// with B-frags loaded straight from pre-packed global Wb/rootb (L1-hot, no staging).
// LDS: SH 40KB union {MTb 64x66 uint (17KB), OUT 64x130 float (33KB)} -> 4 blk/CU.
template <int RELU, int WRITEF, int WRITEB>
__global__ __launch_bounds__(256, 4) void layer_fused(
    const unsigned int* __restrict__ xgb, const int* __restrict__ esrc,
    const int* __restrict__ off,
    const unsigned int* __restrict__ Wb, const unsigned int* __restrict__ rootb,
    const float* __restrict__ bias, float* __restrict__ outf,
    unsigned int* __restrict__ outb) {

    __shared__ unsigned int SH[10240];      // 40960 B

    int tid = threadIdx.x;
    int n0 = blockIdx.x * TILE_N;
    int e = tid & 63, q = tid >> 6;         // gather: lane-node, wave k-quarter
    int w = tid >> 6, l = tid & 63;         // gemm: wave, lane
    int quad = l >> 4, li = l & 15;
    int b = w >> 1;                          // out-half this wave serves

    f32x4 acc[4][2];
#pragma unroll
    for (int s = 0; s < 2; ++s) {
        float bv = bias[32 * w + 16 * s + li];
#pragma unroll
        for (int mt = 0; mt < 4; ++mt) {
            acc[mt][s][0] = bv; acc[mt][s][1] = bv; acc[mt][s][2] = bv; acc[mt][s][3] = bv;
        }
    }

    int node = n0 + e;

    for (int r = 0; r < RR; ++r) {
        // ---- gather mean (bf16 payload, fp32 accum), wave q owns k in [32q,32q+32) ----
        float sA[32];
#pragma unroll
        for (int i = 0; i < 32; ++i) sA[i] = 0.f;
        int ne = 0;
        if (node < NN) {
            int cell = node * RR + r;
            int o = off[cell];
            ne = off[cell + 1] - o;
            int t2 = 0;
            for (; t2 + 2 <= ne; t2 += 2) {
                int s0 = esrc[o + t2], s1 = esrc[o + t2 + 1];
                const uint4* p0 = (const uint4*)(xgb + (size_t)s0 * 64 + q * 16);
                const uint4* p1 = (const uint4*)(xgb + (size_t)s1 * 64 + q * 16);
                uint4 U0[4] = {p0[0], p0[1], p0[2], p0[3]};
                uint4 U1[4] = {p1[0], p1[1], p1[2], p1[3]};
                upadd(sA, U0);
                upadd(sA, U1);
            }
            if (t2 < ne) {
                int s0 = esrc[o + t2];
                const uint4* p0 = (const uint4*)(xgb + (size_t)s0 * 64 + q * 16);
                uint4 U0[4] = {p0[0], p0[1], p0[2], p0[3]};
                upadd(sA, U0);
            }
        }
        float sc = 1.0f / (float)max(ne, 1);
#pragma unroll
        for (int i = 0; i < 16; ++i)
            SH[(16 * q + i) * 66 + e] = packbf2(sA[2 * i] * sc, sA[2 * i + 1] * sc);
        __syncthreads();

        // ---- block-diag GEMM: 16 mfma/wave; A from MTb, B from global Wb (L1-hot) ----
        const uint4* WbB = (const uint4*)(Wb + (((size_t)r * 2 + b) * 64) * 32);
        int nl0 = (w & 1) * 32 + li;         // nloc for s=0
#pragma unroll
        for (int kc = 0; kc < 2; ++kc) {
            ABu bf0, bf1;
            bf0.q = WbB[nl0 * 8 + 4 * kc + quad];
            bf1.q = WbB[(nl0 + 16) * 8 + 4 * kc + quad];
#pragma unroll
            for (int mt = 0; mt < 4; ++mt) {
                ABu af;
                int base = (32 * b + 16 * kc + 4 * quad) * 66 + 16 * mt + li;
                af.q.x = SH[base]; af.q.y = SH[base + 66];
                af.q.z = SH[base + 132]; af.q.w = SH[base + 198];
                acc[mt][0] = __builtin_amdgcn_mfma_f32_16x16x32_bf16(af.v, bf0.v, acc[mt][0], 0, 0, 0);
                acc[mt][1] = __builtin_amdgcn_mfma_f32_16x16x32_bf16(af.v, bf1.v, acc[mt][1], 0, 0, 0);
            }
        }
        __syncthreads();
    }

    // ---- root term: MTb <- own row (already packed bf16: direct copy) ----
    if (node < NN) {
        const uint4* xr = (const uint4*)(xgb + (size_t)node * 64 + q * 16);
        uint4 X[4] = {xr[0], xr[1], xr[2], xr[3]};
#pragma unroll
        for (int i = 0; i < 4; ++i) {
            SH[(16 * q + 4 * i + 0) * 66 + e] = X[i].x;
            SH[(16 * q + 4 * i + 1) * 66 + e] = X[i].y;
            SH[(16 * q + 4 * i + 2) * 66 + e] = X[i].z;
            SH[(16 * q + 4 * i + 3) * 66 + e] = X[i].w;
        }
    } else {
#pragma unroll
        for (int i = 0; i < 16; ++i) SH[(16 * q + i) * 66 + e] = 0u;
    }
    __syncthreads();

    // root GEMM: K=128 -> 4 k-chunks, 32 mfma/wave
    const uint4* RbB = (const uint4*)rootb;
#pragma unroll
    for (int kc = 0; kc < 4; ++kc) {
        ABu bf0, bf1;
        bf0.q = RbB[(32 * w + li) * 16 + 4 * kc + quad];
        bf1.q = RbB[(32 * w + 16 + li) * 16 + 4 * kc + quad];
#pragma unroll
        for (int mt = 0; mt < 4; ++mt) {
            ABu af;
            int base = (16 * kc + 4 * quad) * 66 + 16 * mt + li;
            af.q.x = SH[base]; af.q.y = SH[base + 66];
            af.q.z = SH[base + 132]; af.q.w = SH[base + 198];
            acc[mt][0] = __builtin_amdgcn_mfma_f32_16x16x32_bf16(af.v, bf0.v, acc[mt][0], 0, 0, 0);
            acc[mt][1] = __builtin_amdgcn_mfma_f32_16x16x32_bf16(af.v, bf1.v, acc[mt][1], 0, 0, 0);
        }
    }
    __syncthreads();

    // ---- epilogue: stage D to LDS (fp32, stride 130), then coalesced stores ----
    float* OF = (float*)SH;
#pragma unroll
    for (int mt = 0; mt < 4; ++mt)
#pragma unroll
        for (int s = 0; s < 2; ++s)
#pragma unroll
            for (int reg = 0; reg < 4; ++reg)
                OF[(16 * mt + 4 * quad + reg) * 130 + 32 * w + 16 * s + li] = acc[mt][s][reg];
    __syncthreads();

    if (WRITEB) {
        int p = tid & 63, rg = tid >> 6;     // pair-col, row-group (4 rows/pass)
#pragma unroll 4
        for (int it = 0; it < 16; ++it) {
            int ee = it * 4 + rg, row = n0 + ee;
            if (row < NN) {
                float v0 = OF[ee * 130 + 2 * p], v1 = OF[ee * 130 + 2 * p + 1];
                if (RELU) { v0 = fmaxf(v0, 0.f); v1 = fmaxf(v1, 0.f); }
                outb[(size_t)row * 64 + p] = packbf2(v0, v1);
            }
        }
    }
    if (WRITEF) {
        int d4 = (tid & 31) * 4, rg = tid >> 5;   // 8 rows/pass
#pragma unroll 4
        for (int it = 0; it < 8; ++it) {
            int ee = it * 8 + rg, row = n0 + ee;
            if (row < NN) {
                float4 v = make_float4(OF[ee * 130 + d4], OF[ee * 130 + d4 + 1],
                                       OF[ee * 130 + d4 + 2], OF[ee * 130 + d4 + 3]);
                if (RELU) {
                    v.x = fmaxf(v.x, 0.f); v.y = fmaxf(v.y, 0.f);
                    v.z = fmaxf(v.z, 0.f); v.w = fmaxf(v.w, 0.f);
                }
                *(float4*)(outf + (size_t)row * DD + d4) = v;
            }
        }
    }
}

// ---------------- driver ----------------

extern "C" void kernel_launch(void* const* d_in, const int* in_sizes, int n_in,
                              void* d_out, int out_size, void* d_ws, size_t ws_size,
                              hipStream_t stream) {
    const float* x     = (const float*)d_in[0];
    const int*   ei    = (const int*)d_in[1];
    const int*   src   = ei;
    const int*   dstp  = ei + EE;
    const int*   et    = (const int*)d_in[2];
    const float* W1    = (const float*)d_in[3];
    const float* root1 = (const float*)d_in[4];
    const float* b1    = (const float*)d_in[5];
    const float* W2    = (const float*)d_in[6];
    const float* root2 = (const float*)d_in[7];
    const float* b2    = (const float*)d_in[8];
    float* out = (float*)d_out;

    // ws layout (4 B elements)
    unsigned int* xb  = (unsigned int*)d_ws;         // NN*64 packed bf16 pairs
    unsigned int* hb  = xb + (size_t)NN * 64;        // NN*64
    int* cnt  = (int*)(hb + (size_t)NN * 64);        // CELLS
    int* off  = cnt + CELLS;                         // CELLS + 1
    int* cur  = off + CELLS + 1;                     // CELLS
    int* bsum = cur + CELLS;                         // 512
    int* esrc = bsum + 512;                          // EE
    unsigned int* Wb1 = (unsigned int*)(esrc + EE);  // 32768
    unsigned int* Wb2 = Wb1 + 32768;                 // 32768
    unsigned int* rb1 = Wb2 + 32768;                 // 8192
    unsigned int* rb2 = rb1 + 8192;                  // 8192

    hipMemsetAsync(cnt, 0, CELLS * sizeof(int), stream);
    prep_fused<<<NB_A + NB_B + NB_C + NB_D, 256, 0, stream>>>(
        x, xb, W1, W2, Wb1, Wb2, root1, root2, rb1, rb2, dstp, et, cnt);
    scan1<<<SCAN_BLOCKS, 256, 0, stream>>>(cnt, off, bsum);
    scan2<<<1, 512, 0, stream>>>(bsum);
    scan3<<<SCAN_BLOCKS, 256, 0, stream>>>(off, bsum, cur);
    cell_scatter<<<(EE + 255) / 256, 256, 0, stream>>>(src, dstp, et, cur, esrc);

    // layer 1: bf16 h out;  layer 2: fp32 out
    layer_fused<1, 0, 1><<<NBLK, 256, 0, stream>>>(xb, esrc, off, Wb1, rb1, b1,
                                                   nullptr, hb);
    layer_fused<0, 1, 0><<<NBLK, 256, 0, stream>>>(hb, esrc, off, Wb2, rb2, b2,
                                                   out, nullptr);
}